// Round 7
// baseline (203.445 us; speedup 1.0000x reference)
//
#include <hip/hip_runtime.h>

#define NN 50000
#define KE 32
#define PAD_N 50048     // padded rows per V plane

using f32x4  = __attribute__((ext_vector_type(4))) float;
using bf16x8 = __attribute__((ext_vector_type(8))) short;

__device__ __forceinline__ ushort f2bf(float f) {
    union { float f; unsigned u; } c; c.f = f;
    unsigned u = c.u;
    u += 0x7fffu + ((u >> 16) & 1u);        // round-to-nearest-even
    return (ushort)(u >> 16);
}
__device__ __forceinline__ ushort f2h(float f) {
    union { _Float16 h; ushort u; } c; c.h = (_Float16)f; return c.u;
}
__device__ __forceinline__ float h2f(ushort u) {
    union { ushort u; _Float16 h; } c; c.u = u; return (float)c.h;
}

// Kernel A (blocks 0-1): fold attn_vec through W_q/W_k into bf16 Ub[16][128]
// (cols 0-3 = u_h, 4-7 = v_h, rows 8-15 zeroed for MFMA B-operand).
// Blocks 2..129: cast W_v into Bt[n][k] = bf16(W_v[k][n]).
__global__ __launch_bounds__(256) void prep_kernel(const float* __restrict__ Wq,
        const float* __restrict__ Wk, const float* __restrict__ av,
        const float* __restrict__ Wv, ushort* __restrict__ Ub,
        ushort* __restrict__ Bt) {
    const int g = blockIdx.x * 256 + threadIdx.x;
    if (blockIdx.x < 2) {
        const int h = g >> 7, i = g & 127;
        float su = 0.f, sv = 0.f;
#pragma unroll
        for (int d = 0; d < 32; ++d) {
            su += Wq[i * 128 + h * 32 + d] * av[h * 64 + d];
            sv += Wk[i * 128 + h * 32 + d] * av[h * 64 + 32 + d];
        }
        Ub[h * 128 + i] = f2bf(su);
        Ub[(4 + h) * 128 + i] = f2bf(sv);
        Ub[1024 + g * 2] = 0;               // zero rows 8..15
        Ub[1024 + g * 2 + 1] = 0;
    } else {
        const int idx = g - 512;            // coalesced read of Wv
        const int k = idx >> 7, n = idx & 127;
        Bt[n * 256 + k] = f2bf(Wv[idx]);
    }
}

// Kernel B: V = concat(x, emb) @ W_v via bf16 MFMA + fused sq/sk scores
// (stored [node][4] float4).  V written as 4 column planes (bf16).
__global__ __launch_bounds__(256) void vproj_mfma(const float* __restrict__ x,
        const float* __restrict__ emb, const ushort* __restrict__ Bt,
        const ushort* __restrict__ Ub, float* __restrict__ sq,
        float* __restrict__ sk, ushort* __restrict__ Vp) {
    __shared__ short As[64 * 264];
    const int t = threadIdx.x;
    const int rbase = blockIdx.x * 64;
    const int wv = t >> 6;
    const int lane = t & 63;
    const int lo = lane & 15;
    const int quad = lane >> 4;
    const int c0 = wv * 32;

    // ---- stage A: 64 rows x 256 k, fp32 -> bf16 ----
#pragma unroll
    for (int it = 0; it < 16; ++it) {
        const int li = it * 256 + t;
        const int row = li >> 6;
        const int c4 = li & 63;
        int rg = rbase + row; if (rg >= NN) rg = NN - 1;
        const float* sp = (c4 < 32) ? (x + (long)rg * 128 + c4 * 4)
                                    : (emb + (long)rg * 128 + (c4 - 32) * 4);
        float4 a = *(const float4*)sp;
        ushort4 b = make_ushort4(f2bf(a.x), f2bf(a.y), f2bf(a.z), f2bf(a.w));
        *(ushort4*)&As[row * 264 + c4 * 4] = b;
    }
    // ---- preload all Bt fragments (latency overlaps the barrier) ----
    bf16x8 bt0[8], bt1[8];
#pragma unroll
    for (int ks = 0; ks < 8; ++ks) {
        const int kb = ks * 32 + quad * 8;
        bt0[ks] = *(const bf16x8*)(Bt + (c0 + lo) * 256 + kb);
        bt1[ks] = *(const bf16x8*)(Bt + (c0 + 16 + lo) * 256 + kb);
    }
    __syncthreads();

    f32x4 acc[4][2] = {};
#pragma unroll
    for (int ks = 0; ks < 8; ++ks) {
        const int kb = ks * 32 + quad * 8;
#pragma unroll
        for (int rt = 0; rt < 4; ++rt) {
            bf16x8 af = *(const bf16x8*)&As[(rt * 16 + lo) * 264 + kb];
            acc[rt][0] = __builtin_amdgcn_mfma_f32_16x16x32_bf16(af, bt0[ks], acc[rt][0], 0, 0, 0);
            acc[rt][1] = __builtin_amdgcn_mfma_f32_16x16x32_bf16(af, bt1[ks], acc[rt][1], 0, 0, 0);
        }
    }

    // ---- scores: wave wv handles rows wv*16..+15 (emb half of As) ----
    f32x4 sacc = {};
#pragma unroll
    for (int ks = 0; ks < 4; ++ks) {
        const int kk = ks * 32 + quad * 8;
        bf16x8 saf = *(const bf16x8*)&As[(wv * 16 + lo) * 264 + 128 + kk];
        bf16x8 sbf = *(const bf16x8*)(Ub + lo * 128 + kk);
        sacc = __builtin_amdgcn_mfma_f32_16x16x32_bf16(saf, sbf, sacc, 0, 0, 0);
    }
    if (lo < 8) {
#pragma unroll
        for (int r = 0; r < 4; ++r) {
            const int row = rbase + wv * 16 + quad * 4 + r;
            if (row < NN) {
                if (lo < 4) sq[(long)row * 4 + lo] = sacc[r];
                else        sk[(long)row * 4 + lo - 4] = sacc[r];
            }
        }
    }

    // ---- epilogue: regs -> LDS (stride 132) -> sliced planes ----
    __syncthreads();
#pragma unroll
    for (int rt = 0; rt < 4; ++rt)
#pragma unroll
        for (int ct = 0; ct < 2; ++ct)
#pragma unroll
            for (int r = 0; r < 4; ++r)
                As[(rt * 16 + quad * 4 + r) * 132 + c0 + ct * 16 + lo] =
                    (short)f2bf(acc[rt][ct][r]);
    __syncthreads();
#pragma unroll
    for (int i = 0; i < 4; ++i) {
        const int idx = i * 256 + t;
        const int row = idx >> 4;
        const int seg = idx & 15;           // cols seg*8 .. seg*8+7
        const int grow = rbase + row;
        const int plane = seg >> 2;         // head
        const int pc = (seg & 3) * 8;       // col within plane
        if (grow < NN)
            *(bf16x8*)(Vp + (long)plane * PAD_N * 32 + (long)grow * 32 + pc) =
                *(const bf16x8*)&As[row * 132 + seg * 8];
    }
}

// Kernel C: fully fused aggregate.  Block = 64 nodes (all 4 heads).
// Prologue: no-max softmax for all heads -> fp16 alphas in LDS.
// 4 head-phases (block-synced, start offset by blockIdx%8 for XCD spread):
// each phase gathers one L2-resident 3.2 MB V plane.  Epilogue: ELU +
// LayerNorm (shfl across the node's 4 threads) + direct store to out.
__global__ __launch_bounds__(256) void aggregate2(const int* __restrict__ src,
        const float* __restrict__ sq, const float* __restrict__ sk,
        const ushort* __restrict__ Vp, const float* __restrict__ gamma,
        const float* __restrict__ beta, float* __restrict__ out) {
    __shared__ int    s_src[64 * 33];       //  8448 B
    __shared__ ushort s_al[4][64 * 33];     // 16896 B
    const int b = blockIdx.x;
    const int nbase = b * 64;
    const int t = threadIdx.x;
    const int e = t & 31;

    // ---- prologue: softmax over each node's 32 edges, all 4 heads ----
#pragma unroll
    for (int p = 0; p < 8; ++p) {
        const int slot = p * 8 + (t >> 5);
        const int n = nbase + slot;
        const bool valid = n < NN;
        const int s = valid ? src[(long)n * KE + e] : 0;
        float4 sk4 = *(const float4*)(sk + (long)s * 4);
        float4 sq4 = *(const float4*)(sq + (long)(valid ? n : 0) * 4);
        float ev[4] = { sq4.x + sk4.x, sq4.y + sk4.y, sq4.z + sk4.z, sq4.w + sk4.w };
        float ex[4], sum[4];
#pragma unroll
        for (int h = 0; h < 4; ++h) {
            float v = valid ? (ev[h] > 0.f ? ev[h] : 0.2f * ev[h]) : 0.f;
            ex[h] = __expf(v);              // |v| <= ~6 -> safe without max-sub
            sum[h] = ex[h];
        }
#pragma unroll
        for (int off = 16; off > 0; off >>= 1) {
#pragma unroll
            for (int h = 0; h < 4; ++h) sum[h] += __shfl_xor(sum[h], off);
        }
        s_src[slot * 33 + e] = s;
#pragma unroll
        for (int h = 0; h < 4; ++h)
            s_al[h][slot * 33 + e] = f2h(ex[h] / (sum[h] + 1e-8f));
    }
    __syncthreads();

    // ---- phases: one V plane at a time ----
    const int slot = t >> 2;        // 0..63
    const int l = t & 3;            // cols l*8 .. l*8+7 within a plane
    const int node = nbase + slot;
    int sidx[32];
#pragma unroll
    for (int ee = 0; ee < 32; ++ee) sidx[ee] = s_src[slot * 33 + ee];

    float z[4][8];
    const int hstart = (b & 7) >> 1;
#pragma unroll
    for (int pp = 0; pp < 4; ++pp) {
        const int h = (hstart + pp) & 3;
        const ushort* plane = Vp + (long)h * PAD_N * 32 + l * 8;
        const ushort* alh = &s_al[h][slot * 33];
        float z0 = 0.f, z1 = 0.f, z2 = 0.f, z3 = 0.f;
        float z4 = 0.f, z5 = 0.f, z6 = 0.f, z7 = 0.f;
#pragma unroll
        for (int ee = 0; ee < 32; ++ee) {
            const float a = h2f(alh[ee]);
            uint4 p = *(const uint4*)(plane + (long)sidx[ee] * 32);
            union { unsigned u; float f; } c0e, c0o, c1e, c1o, c2e, c2o, c3e, c3o;
            c0e.u = p.x << 16; c0o.u = p.x & 0xffff0000u;
            c1e.u = p.y << 16; c1o.u = p.y & 0xffff0000u;
            c2e.u = p.z << 16; c2o.u = p.z & 0xffff0000u;
            c3e.u = p.w << 16; c3o.u = p.w & 0xffff0000u;
            z0 += a * c0e.f; z1 += a * c0o.f;
            z2 += a * c1e.f; z3 += a * c1o.f;
            z4 += a * c2e.f; z5 += a * c2o.f;
            z6 += a * c3e.f; z7 += a * c3o.f;
        }
        z[h][0] = z0; z[h][1] = z1; z[h][2] = z2; z[h][3] = z3;
        z[h][4] = z4; z[h][5] = z5; z[h][6] = z6; z[h][7] = z7;
        __syncthreads();                    // keep the block on one plane
    }

    // ---- epilogue: ELU + LayerNorm across the node's 4 threads ----
    float s1 = 0.f, s2 = 0.f;
#pragma unroll
    for (int h = 0; h < 4; ++h)
#pragma unroll
        for (int j = 0; j < 8; ++j) {
            float v = z[h][j];
            v = v > 0.f ? v : __expf(v) - 1.f;
            z[h][j] = v;
            s1 += v;
            s2 += v * v;
        }
    s1 += __shfl_xor(s1, 1); s1 += __shfl_xor(s1, 2);
    s2 += __shfl_xor(s2, 1); s2 += __shfl_xor(s2, 2);
    const float mu = s1 * (1.f / 128.f);
    const float var = s2 * (1.f / 128.f) - mu * mu;
    const float rstd = rsqrtf(var + 1e-5f);
    if (node < NN) {
#pragma unroll
        for (int h = 0; h < 4; ++h) {
            const int c0 = h * 32 + l * 8;
            float4 g0 = *(const float4*)(gamma + c0);
            float4 g1 = *(const float4*)(gamma + c0 + 4);
            float4 b0 = *(const float4*)(beta + c0);
            float4 b1 = *(const float4*)(beta + c0 + 4);
            float* zp = out + (long)node * 128 + c0;
            float4 o0, o1;
            o0.x = (z[h][0] - mu) * rstd * g0.x + b0.x;
            o0.y = (z[h][1] - mu) * rstd * g0.y + b0.y;
            o0.z = (z[h][2] - mu) * rstd * g0.z + b0.z;
            o0.w = (z[h][3] - mu) * rstd * g0.w + b0.w;
            o1.x = (z[h][4] - mu) * rstd * g1.x + b1.x;
            o1.y = (z[h][5] - mu) * rstd * g1.y + b1.y;
            o1.z = (z[h][6] - mu) * rstd * g1.z + b1.z;
            o1.w = (z[h][7] - mu) * rstd * g1.w + b1.w;
            *(float4*)(zp)     = o0;
            *(float4*)(zp + 4) = o1;
        }
    }
}

extern "C" void kernel_launch(void* const* d_in, const int* in_sizes, int n_in,
                              void* d_out, int out_size, void* d_ws, size_t ws_size,
                              hipStream_t stream) {
    const float* x     = (const float*)d_in[0];
    const float* emb   = (const float*)d_in[1];
    const int*   edge  = (const int*)d_in[2];
    const float* Wq    = (const float*)d_in[3];
    const float* Wk    = (const float*)d_in[4];
    const float* Wv    = (const float*)d_in[5];
    const float* av    = (const float*)d_in[6];
    const float* gamma = (const float*)d_in[7];
    const float* beta  = (const float*)d_in[8];
    float* out = (float*)d_out;

    char* ws = (char*)d_ws;
    ushort* Ub = (ushort*)(ws + 0);             //    4 KB
    ushort* Bt = (ushort*)(ws + 4096);          //   64 KB
    float*  sq = (float*)(ws + 69632);          //  800 KB  [node][4]
    float*  sk = (float*)(ws + 869632);         //  800 KB  [node][4]
    ushort* Vp = (ushort*)(ws + 1669632);       // 12.8 MB (4 planes)

    prep_kernel<<<130, 256, 0, stream>>>(Wq, Wk, av, Wv, Ub, Bt);
    vproj_mfma<<<(NN + 63) / 64, 256, 0, stream>>>(x, emb, Bt, Ub, sq, sk, Vp);
    aggregate2<<<(NN + 63) / 64, 256, 0, stream>>>(edge, sq, sk, Vp, gamma, beta, out);
}

// Round 8
// 183.017 us; speedup vs baseline: 1.1116x; 1.1116x over previous
//
#include <hip/hip_runtime.h>

#define NN 50000
#define KE 32

using f32x4  = __attribute__((ext_vector_type(4))) float;
using bf16x8 = __attribute__((ext_vector_type(8))) short;
using f16x8  = __attribute__((ext_vector_type(8))) _Float16;

__device__ __forceinline__ ushort f2bf(float f) {
    union { float f; unsigned u; } c; c.f = f;
    unsigned u = c.u;
    u += 0x7fffu + ((u >> 16) & 1u);        // round-to-nearest-even
    return (ushort)(u >> 16);
}
__device__ __forceinline__ ushort f2h(float f) {
    union { _Float16 h; ushort u; } c; c.h = (_Float16)f; return c.u;
}

// Kernel A (blocks 0-1): fold attn_vec through W_q/W_k into bf16 Ub[16][128]
// (cols 0-3 = u_h, 4-7 = v_h, rows 8-15 zeroed for MFMA B-operand).
// Blocks 2..129: cast W_v into Bt[n][k] = bf16(W_v[k][n]).
__global__ __launch_bounds__(256) void prep_kernel(const float* __restrict__ Wq,
        const float* __restrict__ Wk, const float* __restrict__ av,
        const float* __restrict__ Wv, ushort* __restrict__ Ub,
        ushort* __restrict__ Bt) {
    const int g = blockIdx.x * 256 + threadIdx.x;
    if (blockIdx.x < 2) {
        const int h = g >> 7, i = g & 127;
        float su = 0.f, sv = 0.f;
#pragma unroll
        for (int d = 0; d < 32; ++d) {
            su += Wq[i * 128 + h * 32 + d] * av[h * 64 + d];
            sv += Wk[i * 128 + h * 32 + d] * av[h * 64 + 32 + d];
        }
        Ub[h * 128 + i] = f2bf(su);
        Ub[(4 + h) * 128 + i] = f2bf(sv);
        Ub[1024 + g * 2] = 0;               // zero rows 8..15
        Ub[1024 + g * 2 + 1] = 0;
    } else {
        const int idx = g - 512;            // coalesced read of Wv
        const int k = idx >> 7, n = idx & 127;
        Bt[n * 256 + k] = f2bf(Wv[idx]);
    }
}

// Kernel B: V = concat(x, emb) @ W_v via bf16 MFMA + fused sq/sk scores
// (stored [node][4]).  V stored FP16 flat [node][128].
__global__ __launch_bounds__(256) void vproj_mfma(const float* __restrict__ x,
        const float* __restrict__ emb, const ushort* __restrict__ Bt,
        const ushort* __restrict__ Ub, float* __restrict__ sq,
        float* __restrict__ sk, ushort* __restrict__ Vb) {
    __shared__ short As[64 * 264];
    const int t = threadIdx.x;
    const int rbase = blockIdx.x * 64;
    const int wv = t >> 6;
    const int lane = t & 63;
    const int lo = lane & 15;
    const int quad = lane >> 4;
    const int c0 = wv * 32;

    // ---- stage A: 64 rows x 256 k, fp32 -> bf16 ----
#pragma unroll
    for (int it = 0; it < 16; ++it) {
        const int li = it * 256 + t;
        const int row = li >> 6;
        const int c4 = li & 63;
        int rg = rbase + row; if (rg >= NN) rg = NN - 1;
        const float* sp = (c4 < 32) ? (x + (long)rg * 128 + c4 * 4)
                                    : (emb + (long)rg * 128 + (c4 - 32) * 4);
        float4 a = *(const float4*)sp;
        ushort4 b = make_ushort4(f2bf(a.x), f2bf(a.y), f2bf(a.z), f2bf(a.w));
        *(ushort4*)&As[row * 264 + c4 * 4] = b;
    }
    // ---- preload all Bt fragments (latency overlaps the barrier) ----
    bf16x8 bt0[8], bt1[8];
#pragma unroll
    for (int ks = 0; ks < 8; ++ks) {
        const int kb = ks * 32 + quad * 8;
        bt0[ks] = *(const bf16x8*)(Bt + (c0 + lo) * 256 + kb);
        bt1[ks] = *(const bf16x8*)(Bt + (c0 + 16 + lo) * 256 + kb);
    }
    __syncthreads();

    f32x4 acc[4][2] = {};
#pragma unroll
    for (int ks = 0; ks < 8; ++ks) {
        const int kb = ks * 32 + quad * 8;
#pragma unroll
        for (int rt = 0; rt < 4; ++rt) {
            bf16x8 af = *(const bf16x8*)&As[(rt * 16 + lo) * 264 + kb];
            acc[rt][0] = __builtin_amdgcn_mfma_f32_16x16x32_bf16(af, bt0[ks], acc[rt][0], 0, 0, 0);
            acc[rt][1] = __builtin_amdgcn_mfma_f32_16x16x32_bf16(af, bt1[ks], acc[rt][1], 0, 0, 0);
        }
    }

    // ---- scores: wave wv handles rows wv*16..+15 (emb half of As) ----
    f32x4 sacc = {};
#pragma unroll
    for (int ks = 0; ks < 4; ++ks) {
        const int kk = ks * 32 + quad * 8;
        bf16x8 saf = *(const bf16x8*)&As[(wv * 16 + lo) * 264 + 128 + kk];
        bf16x8 sbf = *(const bf16x8*)(Ub + lo * 128 + kk);
        sacc = __builtin_amdgcn_mfma_f32_16x16x32_bf16(saf, sbf, sacc, 0, 0, 0);
    }
    if (lo < 8) {
#pragma unroll
        for (int r = 0; r < 4; ++r) {
            const int row = rbase + wv * 16 + quad * 4 + r;
            if (row < NN) {
                if (lo < 4) sq[(long)row * 4 + lo] = sacc[r];
                else        sk[(long)row * 4 + lo - 4] = sacc[r];
            }
        }
    }

    // ---- epilogue: regs -> LDS (fp16, stride 132) -> coalesced global ----
    __syncthreads();
#pragma unroll
    for (int rt = 0; rt < 4; ++rt)
#pragma unroll
        for (int ct = 0; ct < 2; ++ct)
#pragma unroll
            for (int r = 0; r < 4; ++r)
                As[(rt * 16 + quad * 4 + r) * 132 + c0 + ct * 16 + lo] =
                    (short)f2h(acc[rt][ct][r]);
    __syncthreads();
#pragma unroll
    for (int i = 0; i < 4; ++i) {
        const int idx = i * 256 + t;
        const int row = idx >> 4;
        const int seg = idx & 15;
        const int grow = rbase + row;
        if (grow < NN)
            *(bf16x8*)(Vb + (long)grow * 128 + seg * 8) =
                *(const bf16x8*)&As[row * 132 + seg * 8];
    }
}

// Kernel C: per-node softmax + weighted gather (fp16 V, uint4 loads, fma_mix
// accumulation) + ELU + LayerNorm.  One wave per node, 4 nodes per block.
__global__ __launch_bounds__(256) void aggregate_kernel(const int* __restrict__ src,
        const float* __restrict__ sq, const float* __restrict__ sk,
        const ushort* __restrict__ Vb, const float* __restrict__ gamma,
        const float* __restrict__ beta, float* __restrict__ out) {
    __shared__ int s_src[4][32];
    __shared__ float4 s_alpha[4][32];
    const int w = threadIdx.x >> 6;
    const int lane = threadIdx.x & 63;
    const int n = blockIdx.x * 4 + w;

    if (lane < 32) {
        const int s = src[(long)n * KE + lane];
        float4 sk4 = *(const float4*)(sk + (long)s * 4);
        float4 sq4 = *(const float4*)(sq + (long)n * 4);
        float e[4] = { sq4.x + sk4.x, sq4.y + sk4.y, sq4.z + sk4.z, sq4.w + sk4.w };
#pragma unroll
        for (int h = 0; h < 4; ++h) e[h] = e[h] > 0.f ? e[h] : 0.2f * e[h];
        float m[4] = { e[0], e[1], e[2], e[3] };
#pragma unroll
        for (int off = 16; off > 0; off >>= 1) {
#pragma unroll
            for (int h = 0; h < 4; ++h) m[h] = fmaxf(m[h], __shfl_xor(m[h], off));
        }
        float ex[4], sum[4];
#pragma unroll
        for (int h = 0; h < 4; ++h) { ex[h] = __expf(e[h] - m[h]); sum[h] = ex[h]; }
#pragma unroll
        for (int off = 16; off > 0; off >>= 1) {
#pragma unroll
            for (int h = 0; h < 4; ++h) sum[h] += __shfl_xor(sum[h], off);
        }
        float4 al;
        al.x = ex[0] / (sum[0] + 1e-8f);
        al.y = ex[1] / (sum[1] + 1e-8f);
        al.z = ex[2] / (sum[2] + 1e-8f);
        al.w = ex[3] / (sum[3] + 1e-8f);
        s_src[w][lane] = s;
        s_alpha[w][lane] = al;
    }
    __syncthreads();

    const int g  = lane >> 4;      // edge subgroup 0..3
    const int li = lane & 15;      // column group: cols li*8 .. li*8+7
    const int h  = li >> 2;        // head of these 8 cols
    float z[8] = {};
#pragma unroll
    for (int it = 0; it < 8; ++it) {
        const int e = it * 4 + g;
        const int s = s_src[w][e];
        const float a = ((const float*)&s_alpha[w][e])[h];
        f16x8 v8 = *(const f16x8*)(Vb + (long)s * 128 + li * 8);
#pragma unroll
        for (int j = 0; j < 8; ++j)
            z[j] += a * (float)v8[j];       // v_fma_mix_f32
    }
    // sum over the 4 edge subgroups (lanes differing in bits 4-5)
#pragma unroll
    for (int j = 0; j < 8; ++j) {
        z[j] += __shfl_xor(z[j], 16);
        z[j] += __shfl_xor(z[j], 32);
    }
    // ELU (replicated across subgroups — consistent)
    float s1 = 0.f, s2 = 0.f;
#pragma unroll
    for (int j = 0; j < 8; ++j) {
        z[j] = z[j] > 0.f ? z[j] : __expf(z[j]) - 1.f;
        s1 += z[j];
        s2 += z[j] * z[j];
    }
    // LayerNorm sums over the 16 column groups
#pragma unroll
    for (int off = 8; off > 0; off >>= 1) {
        s1 += __shfl_xor(s1, off);
        s2 += __shfl_xor(s2, off);
    }
    const float mu = s1 * (1.f / 128.f);
    const float var = s2 * (1.f / 128.f) - mu * mu;
    const float rstd = rsqrtf(var + 1e-5f);
    if (g < 2) {
        const int c0 = li * 8 + g * 4;
        float4 ga = *(const float4*)(gamma + c0);
        float4 be = *(const float4*)(beta + c0);
        float4 o;
        o.x = (z[g * 4 + 0] - mu) * rstd * ga.x + be.x;
        o.y = (z[g * 4 + 1] - mu) * rstd * ga.y + be.y;
        o.z = (z[g * 4 + 2] - mu) * rstd * ga.z + be.z;
        o.w = (z[g * 4 + 3] - mu) * rstd * ga.w + be.w;
        *(float4*)(out + (long)n * 128 + c0) = o;
    }
}

extern "C" void kernel_launch(void* const* d_in, const int* in_sizes, int n_in,
                              void* d_out, int out_size, void* d_ws, size_t ws_size,
                              hipStream_t stream) {
    const float* x     = (const float*)d_in[0];
    const float* emb   = (const float*)d_in[1];
    const int*   edge  = (const int*)d_in[2];
    const float* Wq    = (const float*)d_in[3];
    const float* Wk    = (const float*)d_in[4];
    const float* Wv    = (const float*)d_in[5];
    const float* av    = (const float*)d_in[6];
    const float* gamma = (const float*)d_in[7];
    const float* beta  = (const float*)d_in[8];
    float* out = (float*)d_out;

    char* ws = (char*)d_ws;
    ushort* Ub = (ushort*)(ws + 0);             //    4 KB
    ushort* Bt = (ushort*)(ws + 4096);          //   64 KB
    float*  sq = (float*)(ws + 69632);          //  800 KB  [node][4]
    float*  sk = (float*)(ws + 869632);         //  800 KB  [node][4]
    ushort* Vb = (ushort*)(ws + 1669632);       // 12.8 MB  fp16 [node][128]

    prep_kernel<<<130, 256, 0, stream>>>(Wq, Wk, av, Wv, Ub, Bt);
    vproj_mfma<<<(NN + 63) / 64, 256, 0, stream>>>(x, emb, Bt, Ub, sq, sk, Vb);
    aggregate_kernel<<<NN / 4, 256, 0, stream>>>(edge, sq, sk, Vb, gamma, beta, out);
}